// Round 2
// baseline (21580.434 us; speedup 1.0000x reference)
//
#include <hip/hip_runtime.h>
#include <stdint.h>

typedef __attribute__((ext_vector_type(8))) short short8;
typedef __attribute__((ext_vector_type(4))) float floatx4;

#define DEVINL __device__ __forceinline__

DEVINL unsigned short f2bf(float f) {
    unsigned int u = __float_as_uint(f);
    u += 0x7FFFu + ((u >> 16) & 1u);
    return (unsigned short)(u >> 16);
}
DEVINL float bf2f(unsigned short h) {
    return __uint_as_float(((unsigned int)h) << 16);
}
DEVINL float sigf(float x)     { return 1.0f / (1.0f + __expf(-x)); }
DEVINL float tanhfast(float x) { return 2.0f / (1.0f + __expf(-2.0f * x)) - 1.0f; }

// ---------------- problem constants ----------------
constexpr int L_SEQ = 256, BATCH = 16, HID = 800, NGATE = 3200, DIN = 42, NALPHA = 20;
constexpr int HSLOT = BATCH * HID;          // 12800 elements per time slot
constexpr int NBLK_SCAN = 200;              // 2 dirs x 100 j-chunks (8 hidden units each)

// ---------------- workspace layout (bytes) ----------------
// hi/lo split-bf16 weights + fp32 pre-activations; pre0/pre1 alias one buffer.
constexpr size_t OFF_CNT     = 0;                                   // 256 B counters
constexpr size_t SZ_WHH_L    = 10240000;                            // per layer: 2*3200*800*2B
constexpr size_t OFF_WHH_HI  = 256;                                 // 2 layers
constexpr size_t OFF_WHH_LO  = OFF_WHH_HI + 2 * SZ_WHH_L;
constexpr size_t SZ_WIH1     = 20480000;                            // 2*3200*1600*2B
constexpr size_t OFF_WIH1_HI = OFF_WHH_LO + 2 * SZ_WHH_L;
constexpr size_t OFF_WIH1_LO = OFF_WIH1_HI + SZ_WIH1;
constexpr size_t OFF_PRE     = OFF_WIH1_LO + SZ_WIH1;               // fp32, shared pre0/pre1
constexpr size_t SZ_PRE      = (size_t)2 * L_SEQ * BATCH * NGATE * 4;  // 104,857,600
constexpr size_t SZ_HBUF     = (size_t)257 * HSLOT * 2;             // 6,579,200 per buf
constexpr size_t OFF_H       = OFF_PRE + SZ_PRE;                    // 8 bufs: FHi,FLo,BHi,BLo,2FHi,2FLo,2BHi,2BLo
constexpr size_t OFF_ANG     = OFF_H + 8 * SZ_HBUF;                 // 256*16*3 fp32
// total ~228.4 MiB

// =====================================================================
// Pack W_hh (fp32 [2][3200][800]) into hi/lo MFMA B-fragment streams.
// Block (d,jc) owns hidden units j = jc*8..jc*8+7 -> 32 gate rows as
// 2 N-tiles of 16. Fragment: lane l holds W[r0+(l&15)][k0+(l>>4)*8+0..7].
// =====================================================================
__global__ __launch_bounds__(256) void pack_whh_kernel(
    const float* __restrict__ w0, const float* __restrict__ w1,
    unsigned short* __restrict__ hi, unsigned short* __restrict__ lo)
{
    size_t g = (size_t)blockIdx.x * 256 + threadIdx.x;   // 1,280,000 total
    if (g >= 1280000) return;
    int l = (int)(g & 63);
    size_t gg = g >> 6;                                   // 20000 fragment ids
    int kk = (int)(gg % 25); gg /= 25;
    int nt = (int)(gg % 2);  gg /= 2;
    int jc = (int)(gg % 100); gg /= 100;
    int d  = (int)(gg % 2);
    int layer = (int)(gg / 2);
    const float* W = layer ? w1 : w0;
    int lr = nt * 16 + (l & 15);
    int gate = lr >> 3, jj = lr & 7;
    int r  = gate * 800 + jc * 8 + jj;
    int k0 = kk * 32 + (l >> 4) * 8;
    const float* s = W + ((size_t)d * NGATE + r) * HID + k0;
    short8 vh, vl;
    #pragma unroll
    for (int j = 0; j < 8; ++j) {
        float w = s[j];
        unsigned short h = f2bf(w);
        vh[j] = (short)h;
        vl[j] = (short)f2bf(w - bf2f(h));
    }
    size_t idx = (size_t)layer * 640000 + ((size_t)d * 100 + jc) * 3200
               + (size_t)(nt * 25 + kk) * 64 + l;
    ((short8*)hi)[idx] = vh;
    ((short8*)lo)[idx] = vl;
}

// =====================================================================
// fp32 -> hi/lo bf16 conversion of w_ih_l1 (flat [2][3200][1600]).
// =====================================================================
__global__ __launch_bounds__(256) void conv_wih1_kernel(
    const float* __restrict__ w, unsigned short* __restrict__ hi,
    unsigned short* __restrict__ lo)
{
    size_t g = (size_t)blockIdx.x * 256 + threadIdx.x;   // 1,280,000 groups of 8
    if (g >= 1280000) return;
    const float* s = w + g * 8;
    short8 vh, vl;
    #pragma unroll
    for (int j = 0; j < 8; ++j) {
        float x = s[j];
        unsigned short h = f2bf(x);
        vh[j] = (short)h;
        vl[j] = (short)f2bf(x - bf2f(h));
    }
    ((short8*)hi)[g] = vh;
    ((short8*)lo)[g] = vl;
}

// =====================================================================
// pre0[d][t][b][r] = x[t,b,:] @ w_ih_l0[d].T + b_l0[d]   (fp32 out)
// grid: 1600 blocks = d(2) x rchunk(100 of 32 rows) x tchunk(8 of 32 t)
// =====================================================================
__global__ __launch_bounds__(256) void pre0_kernel(
    const float* __restrict__ x, const float* __restrict__ wih0,
    const float* __restrict__ b0, float* __restrict__ pre0)
{
    int bid = blockIdx.x;
    int d = bid / 800; int rem = bid % 800;
    int rc = rem / 8, tc = rem % 8;
    int rbase = rc * 32, tbase = tc * 32;
    __shared__ float Wc[32][DIN];
    __shared__ float bias[32];
    __shared__ float xb[BATCH][DIN];
    int tid = threadIdx.x;
    for (int idx = tid; idx < 32 * DIN; idx += 256) {
        int rl = idx / DIN, k = idx % DIN;
        Wc[rl][k] = wih0[((size_t)d * NGATE + rbase + rl) * DIN + k];
    }
    if (tid < 32) bias[tid] = b0[d * NGATE + rbase + tid];
    __syncthreads();
    for (int tt = 0; tt < 32; ++tt) {
        int t = tbase + tt;
        for (int idx = tid; idx < BATCH * DIN; idx += 256) {
            int bb = idx / DIN, k = idx % DIN;
            xb[bb][k] = x[((size_t)bb * L_SEQ + t) * DIN + k];
        }
        __syncthreads();
        for (int o = tid; o < 512; o += 256) {
            int bb = o >> 5, rl = o & 31;
            float s = bias[rl];
            #pragma unroll 6
            for (int k = 0; k < DIN; ++k) s += xb[bb][k] * Wc[rl][k];
            pre0[((size_t)(d * L_SEQ + t) * BATCH + bb) * NGATE + rbase + rl] = s;
        }
        __syncthreads();
    }
}

// =====================================================================
// Persistent bidirectional LSTM scan (split-precision bf16 hi/lo).
// 200 blocks: 0..99 fwd, 100..199 bwd. Block (d,jc) owns hidden units
// jc*8..jc*8+7 -> 32 gate rows of W_hh (hi+lo) in LDS.
// Per step: 3-term split MFMA over K=800 (4 waves = 2 N-tiles x 2 K-halves),
// gate fuse (c fp32 in LDS), h -> global hi/lo, device-scope spin barrier.
// =====================================================================
__global__ __launch_bounds__(256, 1) void scan_kernel(
    const unsigned short* __restrict__ wpackH,
    const unsigned short* __restrict__ wpackL,
    const float* __restrict__ pre,              // [d][t][b][3200] fp32
    unsigned short* hFHi, unsigned short* hFLo,
    unsigned short* hBHi, unsigned short* hBLo,
    unsigned int* cnt)
{
    __shared__ __align__(16) unsigned short wldsH[25600];   // 51.2 KB
    __shared__ __align__(16) unsigned short wldsL[25600];   // 51.2 KB
    __shared__ __align__(16) float exch[2][2][64][4];       // [nt][kh][lane][reg]
    __shared__ float cbuf[128];
    int tid = threadIdx.x;
    int bid = blockIdx.x;
    int d = bid / 100, jc = bid % 100;

    {   // load weight fragments once
        const short8* sh = (const short8*)wpackH + ((size_t)d * 100 + jc) * 3200;
        const short8* sl = (const short8*)wpackL + ((size_t)d * 100 + jc) * 3200;
        short8* dh = (short8*)wldsH;
        short8* dl = (short8*)wldsL;
        for (int i = tid; i < 3200; i += 256) { dh[i] = sh[i]; dl[i] = sl[i]; }
    }
    if (tid < 128) cbuf[tid] = 0.0f;
    __syncthreads();

    int lane = tid & 63, w = tid >> 6;
    int nt = w & 1, kh = w >> 1;
    int kkS = kh ? 13 : 0, kkE = kh ? 25 : 13;
    int bA = lane & 15, q = lane >> 4;

    unsigned short* hOutHi = d ? hBHi : hFHi;
    unsigned short* hOutLo = d ? hBLo : hFLo;
    const unsigned short* hInHi = d ? hBHi : hFHi;
    const unsigned short* hInLo = d ? hBLo : hFLo;

    for (int s = 0; s < L_SEQ; ++s) {
        int t = d ? (L_SEQ - 1 - s) : s;
        size_t islot = (size_t)(d ? (t + 1) : t) * HSLOT;
        const unsigned short* hinH = hInHi + islot;
        const unsigned short* hinL = hInLo + islot;

        floatx4 acc = {0.f, 0.f, 0.f, 0.f};
        for (int kk = kkS; kk < kkE; ++kk) {
            int k0 = kk * 32 + q * 8;
            short8 ah = *(const short8*)(hinH + bA * HID + k0);
            short8 al = *(const short8*)(hinL + bA * HID + k0);
            short8 bh = ((const short8*)wldsH)[(nt * 25 + kk) * 64 + lane];
            short8 bl = ((const short8*)wldsL)[(nt * 25 + kk) * 64 + lane];
            acc = __builtin_amdgcn_mfma_f32_16x16x32_bf16(ah, bh, acc, 0, 0, 0);
            acc = __builtin_amdgcn_mfma_f32_16x16x32_bf16(ah, bl, acc, 0, 0, 0);
            acc = __builtin_amdgcn_mfma_f32_16x16x32_bf16(al, bh, acc, 0, 0, 0);
        }
        *(floatx4*)&exch[nt][kh][lane][0] = acc;
        __syncthreads();

        if (tid < 128) {
            int bb = tid >> 3, jl = tid & 7;
            float G[4];
            #pragma unroll
            for (int gate = 0; gate < 4; ++gate) {
                int lr = gate * 8 + jl;
                int nt2 = lr >> 4, n = lr & 15;
                int ln = ((bb >> 2) << 4) | n;
                int rg = bb & 3;
                float pv = pre[((size_t)(d * L_SEQ + t) * BATCH + bb) * NGATE
                               + gate * 800 + jc * 8 + jl];
                G[gate] = exch[nt2][0][ln][rg] + exch[nt2][1][ln][rg] + pv;
            }
            float i_ = sigf(G[0]), f_ = sigf(G[1]);
            float g_ = tanhfast(G[2]), o_ = sigf(G[3]);
            float c = f_ * cbuf[tid] + i_ * g_;
            cbuf[tid] = c;
            float h = o_ * tanhfast(c);
            size_t oslot = (size_t)(d ? t : (t + 1)) * HSLOT;
            size_t oidx = oslot + bb * HID + jc * 8 + jl;
            unsigned short hh = f2bf(h);
            hOutHi[oidx] = hh;
            hOutLo[oidx] = f2bf(h - bf2f(hh));
        }
        __syncthreads();
        __threadfence();                       // release: drain h stores device-scope
        if (tid == 0) {
            __hip_atomic_fetch_add(cnt, 1u, __ATOMIC_RELEASE, __HIP_MEMORY_SCOPE_AGENT);
            unsigned int tgt = (unsigned int)NBLK_SCAN * (unsigned int)(s + 1);
            while (__hip_atomic_load(cnt, __ATOMIC_RELAXED, __HIP_MEMORY_SCOPE_AGENT) < tgt) {}
        }
        __syncthreads();
        __threadfence();                       // acquire
    }
}

// =====================================================================
// pre1[d][t][b][r] = concat(h1f[t], h1b[t]) @ w_ih_l1[d].T + b_l1[d]  (fp32)
// split-precision 64x64-tile MFMA GEMM: M=4096 (t,b), N=3200, K=1600.
// grid: 6400 = d(2) x mblk(64) x nblk(50)
// =====================================================================
__global__ __launch_bounds__(256, 1) void gemm_pre1_kernel(
    const unsigned short* __restrict__ hFHi, const unsigned short* __restrict__ hFLo,
    const unsigned short* __restrict__ hBHi, const unsigned short* __restrict__ hBLo,
    const unsigned short* __restrict__ wih1H, const unsigned short* __restrict__ wih1L,
    const float* __restrict__ b1, float* __restrict__ pre1)
{
    int bid = blockIdx.x;
    int d = bid / 3200; int rst = bid % 3200;
    int mblk = rst / 50, nblk = rst % 50;
    __shared__ __align__(16) unsigned short AslH[64][40];
    __shared__ __align__(16) unsigned short AslL[64][40];
    __shared__ __align__(16) unsigned short BslH[64][40];
    __shared__ __align__(16) unsigned short BslL[64][40];
    int tid = threadIdx.x, lane = tid & 63, w = tid >> 6;
    int wm = w >> 1, wn = w & 1;
    floatx4 acc[2][2] = {};
    int row = tid >> 2, ch = tid & 3;
    int m_row = mblk * 64 + row;
    int t = m_row >> 4, bb = m_row & 15;
    int la = lane & 15, q8 = (lane >> 4) * 8;

    for (int kk = 0; kk < 50; ++kk) {
        int k0 = kk * 32 + ch * 8;
        size_t aoff = (kk < 25)
            ? ((size_t)(t + 1) * HSLOT + bb * HID + k0)
            : ((size_t)t * HSLOT + bb * HID + (k0 - 800));
        const unsigned short* aH = (kk < 25) ? hFHi : hBHi;
        const unsigned short* aL = (kk < 25) ? hFLo : hBLo;
        *(short8*)&AslH[row][ch * 8] = *(const short8*)(aH + aoff);
        *(short8*)&AslL[row][ch * 8] = *(const short8*)(aL + aoff);
        size_t boff = ((size_t)d * NGATE + nblk * 64 + row) * 1600 + kk * 32 + ch * 8;
        *(short8*)&BslH[row][ch * 8] = *(const short8*)(wih1H + boff);
        *(short8*)&BslL[row][ch * 8] = *(const short8*)(wih1L + boff);
        __syncthreads();
        #pragma unroll
        for (int ms = 0; ms < 2; ++ms) {
            short8 ah = *(const short8*)&AslH[wm * 32 + ms * 16 + la][q8];
            short8 al = *(const short8*)&AslL[wm * 32 + ms * 16 + la][q8];
            #pragma unroll
            for (int ns = 0; ns < 2; ++ns) {
                short8 bh = *(const short8*)&BslH[wn * 32 + ns * 16 + la][q8];
                short8 bl = *(const short8*)&BslL[wn * 32 + ns * 16 + la][q8];
                acc[ms][ns] = __builtin_amdgcn_mfma_f32_16x16x32_bf16(ah, bh, acc[ms][ns], 0, 0, 0);
                acc[ms][ns] = __builtin_amdgcn_mfma_f32_16x16x32_bf16(ah, bl, acc[ms][ns], 0, 0, 0);
                acc[ms][ns] = __builtin_amdgcn_mfma_f32_16x16x32_bf16(al, bh, acc[ms][ns], 0, 0, 0);
            }
        }
        __syncthreads();
    }
    #pragma unroll
    for (int ms = 0; ms < 2; ++ms)
        #pragma unroll
        for (int ns = 0; ns < 2; ++ns)
            #pragma unroll
            for (int rg = 0; rg < 4; ++rg) {
                int m = mblk * 64 + wm * 32 + ms * 16 + (lane >> 4) * 4 + rg;
                int t2 = m >> 4, b2 = m & 15;
                int r = nblk * 64 + wn * 32 + ns * 16 + (lane & 15);
                float val = acc[ms][ns][rg] + b1[d * NGATE + r];
                pre1[((size_t)(d * L_SEQ + t2) * BATCH + b2) * NGATE + r] = val;
            }
}

// =====================================================================
// Head: logits -> softmax -> torsion angles.  One block per t.
// =====================================================================
__global__ __launch_bounds__(256) void head_kernel(
    const unsigned short* __restrict__ h2FHi, const unsigned short* __restrict__ h2FLo,
    const unsigned short* __restrict__ h2BHi, const unsigned short* __restrict__ h2BLo,
    const float* __restrict__ wlin, const float* __restrict__ blin,
    const float* __restrict__ alphabet, float* __restrict__ ang)
{
    int t = blockIdx.x, tid = threadIdx.x;
    __shared__ float lg[BATCH * NALPHA];
    __shared__ float probs[BATCH * NALPHA];
    for (int i = tid; i < BATCH * NALPHA; i += 256) {
        int a = i % NALPHA, b = i / NALPHA;
        size_t fo = (size_t)(t + 1) * HSLOT + b * HID;
        size_t bo = (size_t)t * HSLOT + b * HID;
        const float* wa = wlin + (size_t)a * 1600;
        float s = blin[a];
        #pragma unroll 4
        for (int k = 0; k < HID; ++k) {
            float hf = bf2f(h2FHi[fo + k]) + bf2f(h2FLo[fo + k]);
            float hb = bf2f(h2BHi[bo + k]) + bf2f(h2BLo[bo + k]);
            s += hf * wa[k] + hb * wa[800 + k];
        }
        lg[b * NALPHA + a] = s;
    }
    __syncthreads();
    if (tid < BATCH) {
        int b = tid;
        float mx = -1e30f;
        for (int a = 0; a < NALPHA; ++a) mx = fmaxf(mx, lg[b * NALPHA + a]);
        float sum = 0.f;
        for (int a = 0; a < NALPHA; ++a) {
            float e = __expf(lg[b * NALPHA + a] - mx);
            probs[b * NALPHA + a] = e; sum += e;
        }
        float inv = 1.0f / sum;
        for (int a = 0; a < NALPHA; ++a) probs[b * NALPHA + a] *= inv;
    }
    __syncthreads();
    if (tid < BATCH * 3) {
        int b = tid / 3, i = tid % 3;
        float ss = 0.f, cc = 0.f;
        for (int a = 0; a < NALPHA; ++a) {
            float al = alphabet[a * 3 + i], p = probs[b * NALPHA + a];
            ss += p * sinf(al); cc += p * cosf(al);
        }
        ang[((size_t)t * BATCH + b) * 3 + i] = atan2f(ss, cc);
    }
}

// =====================================================================
// Sequential NeRF coordinate chain. One block; lane b handles batch b.
// =====================================================================
__global__ __launch_bounds__(64) void coords_kernel(
    const float* __restrict__ ang, float* __restrict__ out)
{
    int b = threadIdx.x;
    if (b >= BATCH) return;
    const float LENS[3] = {145.801f, 152.326f, 132.868f};
    const float ANGS[3] = {2.124f, 1.941f, 2.028f};
    float Ax = 0.f, Ay = 0.f, Az = 1.f;
    float Bx = 0.f, By = 1.f, Bz = 0.f;
    float Cx = 1.f, Cy = 0.f, Cz = 0.f;
    out[((size_t)0 * BATCH + b) * 3 + 0] = 0.f; out[((size_t)0 * BATCH + b) * 3 + 1] = 0.f; out[((size_t)0 * BATCH + b) * 3 + 2] = 1.f;
    out[((size_t)1 * BATCH + b) * 3 + 0] = 0.f; out[((size_t)1 * BATCH + b) * 3 + 1] = 1.f; out[((size_t)1 * BATCH + b) * 3 + 2] = 0.f;
    out[((size_t)2 * BATCH + b) * 3 + 0] = 1.f; out[((size_t)2 * BATCH + b) * 3 + 1] = 0.f; out[((size_t)2 * BATCH + b) * 3 + 2] = 0.f;
    for (int t = 0; t < L_SEQ; ++t) {
        #pragma unroll
        for (int i = 0; i < 3; ++i) {
            float P = ang[((size_t)t * BATCH + b) * 3 + i];
            float R = LENS[i], T = ANGS[i];
            float sT = sinf(T);
            float D2x = -R * cosf(T);
            float D2y = R * cosf(P) * sT;
            float D2z = R * sinf(P) * sT;
            float bx = Cx - Bx, by = Cy - By, bz = Cz - Bz;
            float binv = 1.0f / sqrtf(bx * bx + by * by + bz * bz);
            bx *= binv; by *= binv; bz *= binv;
            float ux = Bx - Ax, uy = By - Ay, uz = Bz - Az;
            float nx = uy * bz - uz * by;
            float ny = uz * bx - ux * bz;
            float nz = ux * by - uy * bx;
            float ninv = 1.0f / sqrtf(nx * nx + ny * ny + nz * nz);
            nx *= ninv; ny *= ninv; nz *= ninv;
            float cxx = ny * bz - nz * by;
            float cxy = nz * bx - nx * bz;
            float cxz = nx * by - ny * bx;
            float Dx = bx * D2x + cxx * D2y + nx * D2z + Cx;
            float Dy = by * D2x + cxy * D2y + ny * D2z + Cy;
            float Dz = bz * D2x + cxz * D2y + nz * D2z + Cz;
            size_t orow = 3 + (size_t)t * 3 + i;
            out[(orow * BATCH + b) * 3 + 0] = Dx;
            out[(orow * BATCH + b) * 3 + 1] = Dy;
            out[(orow * BATCH + b) * 3 + 2] = Dz;
            Ax = Bx; Ay = By; Az = Bz;
            Bx = Cx; By = Cy; Bz = Cz;
            Cx = Dx; Cy = Dy; Cz = Dz;
        }
    }
}

// =====================================================================
extern "C" void kernel_launch(void* const* d_in, const int* in_sizes, int n_in,
                              void* d_out, int out_size, void* d_ws, size_t ws_size,
                              hipStream_t stream)
{
    const float* x       = (const float*)d_in[0];
    const float* w_ih_l0 = (const float*)d_in[1];
    const float* w_hh_l0 = (const float*)d_in[2];
    const float* b_l0    = (const float*)d_in[3];
    const float* w_ih_l1 = (const float*)d_in[4];
    const float* w_hh_l1 = (const float*)d_in[5];
    const float* b_l1    = (const float*)d_in[6];
    const float* w_lin   = (const float*)d_in[7];
    const float* b_lin   = (const float*)d_in[8];
    const float* alphabet= (const float*)d_in[9];
    (void)in_sizes; (void)n_in; (void)out_size; (void)ws_size;

    char* ws = (char*)d_ws;
    unsigned int*   cnt     = (unsigned int*)(ws + OFF_CNT);
    unsigned short* whhHi   = (unsigned short*)(ws + OFF_WHH_HI);
    unsigned short* whhLo   = (unsigned short*)(ws + OFF_WHH_LO);
    unsigned short* wih1Hi  = (unsigned short*)(ws + OFF_WIH1_HI);
    unsigned short* wih1Lo  = (unsigned short*)(ws + OFF_WIH1_LO);
    float*          pre     = (float*)(ws + OFF_PRE);       // pre0 then pre1 (aliased)
    unsigned short* hFHi    = (unsigned short*)(ws + OFF_H + 0 * SZ_HBUF);
    unsigned short* hFLo    = (unsigned short*)(ws + OFF_H + 1 * SZ_HBUF);
    unsigned short* hBHi    = (unsigned short*)(ws + OFF_H + 2 * SZ_HBUF);
    unsigned short* hBLo    = (unsigned short*)(ws + OFF_H + 3 * SZ_HBUF);
    unsigned short* h2FHi   = (unsigned short*)(ws + OFF_H + 4 * SZ_HBUF);
    unsigned short* h2FLo   = (unsigned short*)(ws + OFF_H + 5 * SZ_HBUF);
    unsigned short* h2BHi   = (unsigned short*)(ws + OFF_H + 6 * SZ_HBUF);
    unsigned short* h2BLo   = (unsigned short*)(ws + OFF_H + 7 * SZ_HBUF);
    float*          angbuf  = (float*)(ws + OFF_ANG);

    // zero barrier counters + boundary h slots (slot 0 for F bufs, slot 256 for B bufs)
    hipMemsetAsync(ws + OFF_CNT, 0, 256, stream);
    const size_t slotB = (size_t)HSLOT * 2;
    hipMemsetAsync((char*)hFHi, 0, slotB, stream);
    hipMemsetAsync((char*)hFLo, 0, slotB, stream);
    hipMemsetAsync((char*)hBHi + 256 * slotB, 0, slotB, stream);
    hipMemsetAsync((char*)hBLo + 256 * slotB, 0, slotB, stream);
    hipMemsetAsync((char*)h2FHi, 0, slotB, stream);
    hipMemsetAsync((char*)h2FLo, 0, slotB, stream);
    hipMemsetAsync((char*)h2BHi + 256 * slotB, 0, slotB, stream);
    hipMemsetAsync((char*)h2BLo + 256 * slotB, 0, slotB, stream);

    pack_whh_kernel<<<5000, 256, 0, stream>>>(w_hh_l0, w_hh_l1, whhHi, whhLo);
    conv_wih1_kernel<<<5000, 256, 0, stream>>>(w_ih_l1, wih1Hi, wih1Lo);
    pre0_kernel<<<1600, 256, 0, stream>>>(x, w_ih_l0, b_l0, pre);

    // layer 0 bidirectional scan
    scan_kernel<<<NBLK_SCAN, 256, 0, stream>>>(whhHi, whhLo, pre, hFHi, hFLo, hBHi, hBLo, cnt);
    // layer 1 input projection (overwrites pre in place: pre0 dead, pre1 live)
    gemm_pre1_kernel<<<6400, 256, 0, stream>>>(hFHi, hFLo, hBHi, hBLo,
                                               wih1Hi, wih1Lo, b_l1, pre);
    // layer 1 bidirectional scan (layer-1 weight base; fresh counter cacheline)
    constexpr size_t LOFF = SZ_WHH_L / 2;  // ushort elements per layer
    scan_kernel<<<NBLK_SCAN, 256, 0, stream>>>(whhHi + LOFF, whhLo + LOFF, pre,
                                               h2FHi, h2FLo, h2BHi, h2BLo, cnt + 32);

    head_kernel<<<L_SEQ, 256, 0, stream>>>(h2FHi, h2FLo, h2BHi, h2BLo,
                                           w_lin, b_lin, alphabet, angbuf);
    coords_kernel<<<1, 64, 0, stream>>>(angbuf, (float*)d_out);
}

// Round 3
// 12862.834 us; speedup vs baseline: 1.6777x; 1.6777x over previous
//
#include <hip/hip_runtime.h>
#include <stdint.h>

typedef __attribute__((ext_vector_type(8))) short short8;
typedef __attribute__((ext_vector_type(4))) float floatx4;

#define DEVINL __device__ __forceinline__

DEVINL unsigned short f2bf(float f) {
    unsigned int u = __float_as_uint(f);
    u += 0x7FFFu + ((u >> 16) & 1u);
    return (unsigned short)(u >> 16);
}
DEVINL float bf2f(unsigned short h) {
    return __uint_as_float(((unsigned int)h) << 16);
}
DEVINL float sigf(float x)     { return 1.0f / (1.0f + __expf(-x)); }
DEVINL float tanhfast(float x) { return 2.0f / (1.0f + __expf(-2.0f * x)) - 1.0f; }

// ---------------- problem constants ----------------
constexpr int L_SEQ = 256, BATCH = 16, HID = 800, NGATE = 3200, DIN = 42, NALPHA = 20;
constexpr int HSLOT = BATCH * HID;          // 12800 elements per time slot
constexpr int NBLK_SCAN = 200;              // 2 dirs x 100 j-chunks (8 hidden units each)

// ---------------- workspace layout (bytes) ----------------
// hi/lo split-bf16 weights + fp32 pre-activations; pre0/pre1 alias one buffer.
constexpr size_t OFF_CNT     = 0;                                   // 4 KB flag arrays
constexpr size_t SZ_WHH_L    = 10240000;                            // per layer: 2*3200*800*2B
constexpr size_t OFF_WHH_HI  = 4096;                                // 2 layers
constexpr size_t OFF_WHH_LO  = OFF_WHH_HI + 2 * SZ_WHH_L;
constexpr size_t SZ_WIH1     = 20480000;                            // 2*3200*1600*2B
constexpr size_t OFF_WIH1_HI = OFF_WHH_LO + 2 * SZ_WHH_L;
constexpr size_t OFF_WIH1_LO = OFF_WIH1_HI + SZ_WIH1;
constexpr size_t OFF_PRE     = OFF_WIH1_LO + SZ_WIH1;               // fp32, shared pre0/pre1
constexpr size_t SZ_PRE      = (size_t)2 * L_SEQ * BATCH * NGATE * 4;  // 104,857,600
constexpr size_t SZ_HBUF     = (size_t)257 * HSLOT * 2;             // 6,579,200 per buf
constexpr size_t OFF_H       = OFF_PRE + SZ_PRE;                    // 8 bufs
constexpr size_t OFF_ANG     = OFF_H + 8 * SZ_HBUF;                 // 256*16*3 fp32
// total ~228.4 MiB

// =====================================================================
// Pack W_hh (fp32 [2][3200][800]) into hi/lo MFMA B-fragment streams.
// =====================================================================
__global__ __launch_bounds__(256) void pack_whh_kernel(
    const float* __restrict__ w0, const float* __restrict__ w1,
    unsigned short* __restrict__ hi, unsigned short* __restrict__ lo)
{
    size_t g = (size_t)blockIdx.x * 256 + threadIdx.x;   // 1,280,000 total
    if (g >= 1280000) return;
    int l = (int)(g & 63);
    size_t gg = g >> 6;                                   // 20000 fragment ids
    int kk = (int)(gg % 25); gg /= 25;
    int nt = (int)(gg % 2);  gg /= 2;
    int jc = (int)(gg % 100); gg /= 100;
    int d  = (int)(gg % 2);
    int layer = (int)(gg / 2);
    const float* W = layer ? w1 : w0;
    int lr = nt * 16 + (l & 15);
    int gate = lr >> 3, jj = lr & 7;
    int r  = gate * 800 + jc * 8 + jj;
    int k0 = kk * 32 + (l >> 4) * 8;
    const float* s = W + ((size_t)d * NGATE + r) * HID + k0;
    short8 vh, vl;
    #pragma unroll
    for (int j = 0; j < 8; ++j) {
        float w = s[j];
        unsigned short h = f2bf(w);
        vh[j] = (short)h;
        vl[j] = (short)f2bf(w - bf2f(h));
    }
    size_t idx = (size_t)layer * 640000 + ((size_t)d * 100 + jc) * 3200
               + (size_t)(nt * 25 + kk) * 64 + l;
    ((short8*)hi)[idx] = vh;
    ((short8*)lo)[idx] = vl;
}

// =====================================================================
// fp32 -> hi/lo bf16 conversion of w_ih_l1 (flat [2][3200][1600]).
// =====================================================================
__global__ __launch_bounds__(256) void conv_wih1_kernel(
    const float* __restrict__ w, unsigned short* __restrict__ hi,
    unsigned short* __restrict__ lo)
{
    size_t g = (size_t)blockIdx.x * 256 + threadIdx.x;   // 1,280,000 groups of 8
    if (g >= 1280000) return;
    const float* s = w + g * 8;
    short8 vh, vl;
    #pragma unroll
    for (int j = 0; j < 8; ++j) {
        float x = s[j];
        unsigned short h = f2bf(x);
        vh[j] = (short)h;
        vl[j] = (short)f2bf(x - bf2f(h));
    }
    ((short8*)hi)[g] = vh;
    ((short8*)lo)[g] = vl;
}

// =====================================================================
// pre0[d][t][b][r] = x[t,b,:] @ w_ih_l0[d].T + b_l0[d]   (fp32 out)
// =====================================================================
__global__ __launch_bounds__(256) void pre0_kernel(
    const float* __restrict__ x, const float* __restrict__ wih0,
    const float* __restrict__ b0, float* __restrict__ pre0)
{
    int bid = blockIdx.x;
    int d = bid / 800; int rem = bid % 800;
    int rc = rem / 8, tc = rem % 8;
    int rbase = rc * 32, tbase = tc * 32;
    __shared__ float Wc[32][DIN];
    __shared__ float bias[32];
    __shared__ float xb[BATCH][DIN];
    int tid = threadIdx.x;
    for (int idx = tid; idx < 32 * DIN; idx += 256) {
        int rl = idx / DIN, k = idx % DIN;
        Wc[rl][k] = wih0[((size_t)d * NGATE + rbase + rl) * DIN + k];
    }
    if (tid < 32) bias[tid] = b0[d * NGATE + rbase + tid];
    __syncthreads();
    for (int tt = 0; tt < 32; ++tt) {
        int t = tbase + tt;
        for (int idx = tid; idx < BATCH * DIN; idx += 256) {
            int bb = idx / DIN, k = idx % DIN;
            xb[bb][k] = x[((size_t)bb * L_SEQ + t) * DIN + k];
        }
        __syncthreads();
        for (int o = tid; o < 512; o += 256) {
            int bb = o >> 5, rl = o & 31;
            float s = bias[rl];
            #pragma unroll 6
            for (int k = 0; k < DIN; ++k) s += xb[bb][k] * Wc[rl][k];
            pre0[((size_t)(d * L_SEQ + t) * BATCH + bb) * NGATE + rbase + rl] = s;
        }
        __syncthreads();
    }
}

// =====================================================================
// Persistent bidirectional LSTM scan (split-precision bf16 hi/lo).
// 200 blocks: 0..99 fwd, 100..199 bwd (independent chains, independent
// barriers). Block (d,jc) owns hidden units jc*8..jc*8+7.
// Barrier: contention-free flag array. Each block release-stores its own
// flag word; wave 0 polls all 100 same-direction flags in parallel.
// =====================================================================
__global__ __launch_bounds__(256, 1) void scan_kernel(
    const unsigned short* __restrict__ wpackH,
    const unsigned short* __restrict__ wpackL,
    const float* __restrict__ pre,              // [d][t][b][3200] fp32
    unsigned short* hFHi, unsigned short* hFLo,
    unsigned short* hBHi, unsigned short* hBLo,
    unsigned int* flags)                        // [2][256] uints, per-dir
{
    __shared__ __align__(16) unsigned short wldsH[25600];   // 51.2 KB
    __shared__ __align__(16) unsigned short wldsL[25600];   // 51.2 KB
    __shared__ __align__(16) float exch[2][2][64][4];       // [nt][kh][lane][reg]
    __shared__ float cbuf[128];
    int tid = threadIdx.x;
    int bid = blockIdx.x;
    int d = bid / 100, jc = bid % 100;
    unsigned int* dirFlags = flags + (size_t)d * 256;

    {   // load weight fragments once
        const short8* sh = (const short8*)wpackH + ((size_t)d * 100 + jc) * 3200;
        const short8* sl = (const short8*)wpackL + ((size_t)d * 100 + jc) * 3200;
        short8* dh = (short8*)wldsH;
        short8* dl = (short8*)wldsL;
        for (int i = tid; i < 3200; i += 256) { dh[i] = sh[i]; dl[i] = sl[i]; }
    }
    if (tid < 128) cbuf[tid] = 0.0f;
    __syncthreads();

    int lane = tid & 63, w = tid >> 6;
    int nt = w & 1, kh = w >> 1;
    int kkS = kh ? 13 : 0, kkE = kh ? 25 : 13;
    int bA = lane & 15, q = lane >> 4;

    unsigned short* hOutHi = d ? hBHi : hFHi;
    unsigned short* hOutLo = d ? hBLo : hFLo;
    const unsigned short* hInHi = d ? hBHi : hFHi;
    const unsigned short* hInLo = d ? hBLo : hFLo;

    for (int s = 0; s < L_SEQ; ++s) {
        int t = d ? (L_SEQ - 1 - s) : s;
        size_t islot = (size_t)(d ? (t + 1) : t) * HSLOT;
        const unsigned short* hinH = hInHi + islot;
        const unsigned short* hinL = hInLo + islot;

        floatx4 acc = {0.f, 0.f, 0.f, 0.f};
        for (int kk = kkS; kk < kkE; ++kk) {
            int k0 = kk * 32 + q * 8;
            short8 ah = *(const short8*)(hinH + bA * HID + k0);
            short8 al = *(const short8*)(hinL + bA * HID + k0);
            short8 bh = ((const short8*)wldsH)[(nt * 25 + kk) * 64 + lane];
            short8 bl = ((const short8*)wldsL)[(nt * 25 + kk) * 64 + lane];
            acc = __builtin_amdgcn_mfma_f32_16x16x32_bf16(ah, bh, acc, 0, 0, 0);
            acc = __builtin_amdgcn_mfma_f32_16x16x32_bf16(ah, bl, acc, 0, 0, 0);
            acc = __builtin_amdgcn_mfma_f32_16x16x32_bf16(al, bh, acc, 0, 0, 0);
        }
        *(floatx4*)&exch[nt][kh][lane][0] = acc;
        __syncthreads();

        if (tid < 128) {
            int bb = tid >> 3, jl = tid & 7;
            float G[4];
            #pragma unroll
            for (int gate = 0; gate < 4; ++gate) {
                int lr = gate * 8 + jl;
                int nt2 = lr >> 4, n = lr & 15;
                int ln = ((bb >> 2) << 4) | n;
                int rg = bb & 3;
                float pv = pre[((size_t)(d * L_SEQ + t) * BATCH + bb) * NGATE
                               + gate * 800 + jc * 8 + jl];
                G[gate] = exch[nt2][0][ln][rg] + exch[nt2][1][ln][rg] + pv;
            }
            float i_ = sigf(G[0]), f_ = sigf(G[1]);
            float g_ = tanhfast(G[2]), o_ = sigf(G[3]);
            float c = f_ * cbuf[tid] + i_ * g_;
            cbuf[tid] = c;
            float h = o_ * tanhfast(c);
            size_t oslot = (size_t)(d ? t : (t + 1)) * HSLOT;
            size_t oidx = oslot + bb * HID + jc * 8 + jl;
            unsigned short hh = f2bf(h);
            hOutHi[oidx] = hh;
            hOutLo[oidx] = f2bf(h - bf2f(hh));
        }
        __syncthreads();   // all waves' h stores drained (implicit vmcnt(0) at barrier)

        unsigned int tgt = (unsigned int)(s + 1);
        if (tid == 0) {
            __threadfence();   // release: flush this XCD's L2 so h is device-visible
            __hip_atomic_store(&dirFlags[jc], tgt, __ATOMIC_RELAXED,
                               __HIP_MEMORY_SCOPE_AGENT);
        }
        if (tid < 64) {        // wave 0 polls all 100 flags in parallel
            bool ok;
            do {
                bool a = (tid < 100)
                    ? (__hip_atomic_load(&dirFlags[tid], __ATOMIC_RELAXED,
                                         __HIP_MEMORY_SCOPE_AGENT) >= tgt) : true;
                bool b = (tid + 64 < 100)
                    ? (__hip_atomic_load(&dirFlags[tid + 64], __ATOMIC_RELAXED,
                                         __HIP_MEMORY_SCOPE_AGENT) >= tgt) : true;
                ok = __all(a && b);
            } while (!ok);
        }
        __syncthreads();
        __threadfence();       // acquire: invalidate stale L1/L2 before next h read
    }
}

// =====================================================================
// pre1[d][t][b][r] = concat(h1f[t], h1b[t]) @ w_ih_l1[d].T + b_l1[d]  (fp32)
// split-precision 64x64-tile MFMA GEMM: M=4096 (t,b), N=3200, K=1600.
// =====================================================================
__global__ __launch_bounds__(256, 1) void gemm_pre1_kernel(
    const unsigned short* __restrict__ hFHi, const unsigned short* __restrict__ hFLo,
    const unsigned short* __restrict__ hBHi, const unsigned short* __restrict__ hBLo,
    const unsigned short* __restrict__ wih1H, const unsigned short* __restrict__ wih1L,
    const float* __restrict__ b1, float* __restrict__ pre1)
{
    int bid = blockIdx.x;
    int d = bid / 3200; int rst = bid % 3200;
    int mblk = rst / 50, nblk = rst % 50;
    __shared__ __align__(16) unsigned short AslH[64][40];
    __shared__ __align__(16) unsigned short AslL[64][40];
    __shared__ __align__(16) unsigned short BslH[64][40];
    __shared__ __align__(16) unsigned short BslL[64][40];
    int tid = threadIdx.x, lane = tid & 63, w = tid >> 6;
    int wm = w >> 1, wn = w & 1;
    floatx4 acc[2][2] = {};
    int row = tid >> 2, ch = tid & 3;
    int m_row = mblk * 64 + row;
    int t = m_row >> 4, bb = m_row & 15;
    int la = lane & 15, q8 = (lane >> 4) * 8;

    for (int kk = 0; kk < 50; ++kk) {
        int k0 = kk * 32 + ch * 8;
        size_t aoff = (kk < 25)
            ? ((size_t)(t + 1) * HSLOT + bb * HID + k0)
            : ((size_t)t * HSLOT + bb * HID + (k0 - 800));
        const unsigned short* aH = (kk < 25) ? hFHi : hBHi;
        const unsigned short* aL = (kk < 25) ? hFLo : hBLo;
        *(short8*)&AslH[row][ch * 8] = *(const short8*)(aH + aoff);
        *(short8*)&AslL[row][ch * 8] = *(const short8*)(aL + aoff);
        size_t boff = ((size_t)d * NGATE + nblk * 64 + row) * 1600 + kk * 32 + ch * 8;
        *(short8*)&BslH[row][ch * 8] = *(const short8*)(wih1H + boff);
        *(short8*)&BslL[row][ch * 8] = *(const short8*)(wih1L + boff);
        __syncthreads();
        #pragma unroll
        for (int ms = 0; ms < 2; ++ms) {
            short8 ah = *(const short8*)&AslH[wm * 32 + ms * 16 + la][q8];
            short8 al = *(const short8*)&AslL[wm * 32 + ms * 16 + la][q8];
            #pragma unroll
            for (int ns = 0; ns < 2; ++ns) {
                short8 bh = *(const short8*)&BslH[wn * 32 + ns * 16 + la][q8];
                short8 bl = *(const short8*)&BslL[wn * 32 + ns * 16 + la][q8];
                acc[ms][ns] = __builtin_amdgcn_mfma_f32_16x16x32_bf16(ah, bh, acc[ms][ns], 0, 0, 0);
                acc[ms][ns] = __builtin_amdgcn_mfma_f32_16x16x32_bf16(ah, bl, acc[ms][ns], 0, 0, 0);
                acc[ms][ns] = __builtin_amdgcn_mfma_f32_16x16x32_bf16(al, bh, acc[ms][ns], 0, 0, 0);
            }
        }
        __syncthreads();
    }
    #pragma unroll
    for (int ms = 0; ms < 2; ++ms)
        #pragma unroll
        for (int ns = 0; ns < 2; ++ns)
            #pragma unroll
            for (int rg = 0; rg < 4; ++rg) {
                int m = mblk * 64 + wm * 32 + ms * 16 + (lane >> 4) * 4 + rg;
                int t2 = m >> 4, b2 = m & 15;
                int r = nblk * 64 + wn * 32 + ns * 16 + (lane & 15);
                float val = acc[ms][ns][rg] + b1[d * NGATE + r];
                pre1[((size_t)(d * L_SEQ + t2) * BATCH + b2) * NGATE + r] = val;
            }
}

// =====================================================================
// Head: logits -> softmax -> torsion angles.  One block per t.
// =====================================================================
__global__ __launch_bounds__(256) void head_kernel(
    const unsigned short* __restrict__ h2FHi, const unsigned short* __restrict__ h2FLo,
    const unsigned short* __restrict__ h2BHi, const unsigned short* __restrict__ h2BLo,
    const float* __restrict__ wlin, const float* __restrict__ blin,
    const float* __restrict__ alphabet, float* __restrict__ ang)
{
    int t = blockIdx.x, tid = threadIdx.x;
    __shared__ float lg[BATCH * NALPHA];
    __shared__ float probs[BATCH * NALPHA];
    for (int i = tid; i < BATCH * NALPHA; i += 256) {
        int a = i % NALPHA, b = i / NALPHA;
        size_t fo = (size_t)(t + 1) * HSLOT + b * HID;
        size_t bo = (size_t)t * HSLOT + b * HID;
        const float* wa = wlin + (size_t)a * 1600;
        float s = blin[a];
        #pragma unroll 4
        for (int k = 0; k < HID; ++k) {
            float hf = bf2f(h2FHi[fo + k]) + bf2f(h2FLo[fo + k]);
            float hb = bf2f(h2BHi[bo + k]) + bf2f(h2BLo[bo + k]);
            s += hf * wa[k] + hb * wa[800 + k];
        }
        lg[b * NALPHA + a] = s;
    }
    __syncthreads();
    if (tid < BATCH) {
        int b = tid;
        float mx = -1e30f;
        for (int a = 0; a < NALPHA; ++a) mx = fmaxf(mx, lg[b * NALPHA + a]);
        float sum = 0.f;
        for (int a = 0; a < NALPHA; ++a) {
            float e = __expf(lg[b * NALPHA + a] - mx);
            probs[b * NALPHA + a] = e; sum += e;
        }
        float inv = 1.0f / sum;
        for (int a = 0; a < NALPHA; ++a) probs[b * NALPHA + a] *= inv;
    }
    __syncthreads();
    if (tid < BATCH * 3) {
        int b = tid / 3, i = tid % 3;
        float ss = 0.f, cc = 0.f;
        for (int a = 0; a < NALPHA; ++a) {
            float al = alphabet[a * 3 + i], p = probs[b * NALPHA + a];
            ss += p * sinf(al); cc += p * cosf(al);
        }
        ang[((size_t)t * BATCH + b) * 3 + i] = atan2f(ss, cc);
    }
}

// =====================================================================
// Sequential NeRF coordinate chain. One block; lane b handles batch b.
// =====================================================================
__global__ __launch_bounds__(64) void coords_kernel(
    const float* __restrict__ ang, float* __restrict__ out)
{
    int b = threadIdx.x;
    if (b >= BATCH) return;
    const float LENS[3] = {145.801f, 152.326f, 132.868f};
    const float ANGS[3] = {2.124f, 1.941f, 2.028f};
    float Ax = 0.f, Ay = 0.f, Az = 1.f;
    float Bx = 0.f, By = 1.f, Bz = 0.f;
    float Cx = 1.f, Cy = 0.f, Cz = 0.f;
    out[((size_t)0 * BATCH + b) * 3 + 0] = 0.f; out[((size_t)0 * BATCH + b) * 3 + 1] = 0.f; out[((size_t)0 * BATCH + b) * 3 + 2] = 1.f;
    out[((size_t)1 * BATCH + b) * 3 + 0] = 0.f; out[((size_t)1 * BATCH + b) * 3 + 1] = 1.f; out[((size_t)1 * BATCH + b) * 3 + 2] = 0.f;
    out[((size_t)2 * BATCH + b) * 3 + 0] = 1.f; out[((size_t)2 * BATCH + b) * 3 + 1] = 0.f; out[((size_t)2 * BATCH + b) * 3 + 2] = 0.f;
    for (int t = 0; t < L_SEQ; ++t) {
        #pragma unroll
        for (int i = 0; i < 3; ++i) {
            float P = ang[((size_t)t * BATCH + b) * 3 + i];
            float R = LENS[i], T = ANGS[i];
            float sT = sinf(T);
            float D2x = -R * cosf(T);
            float D2y = R * cosf(P) * sT;
            float D2z = R * sinf(P) * sT;
            float bx = Cx - Bx, by = Cy - By, bz = Cz - Bz;
            float binv = 1.0f / sqrtf(bx * bx + by * by + bz * bz);
            bx *= binv; by *= binv; bz *= binv;
            float ux = Bx - Ax, uy = By - Ay, uz = Bz - Az;
            float nx = uy * bz - uz * by;
            float ny = uz * bx - ux * bz;
            float nz = ux * by - uy * bx;
            float ninv = 1.0f / sqrtf(nx * nx + ny * ny + nz * nz);
            nx *= ninv; ny *= ninv; nz *= ninv;
            float cxx = ny * bz - nz * by;
            float cxy = nz * bx - nx * bz;
            float cxz = nx * by - ny * bx;
            float Dx = bx * D2x + cxx * D2y + nx * D2z + Cx;
            float Dy = by * D2x + cxy * D2y + ny * D2z + Cy;
            float Dz = bz * D2x + cxz * D2y + nz * D2z + Cz;
            size_t orow = 3 + (size_t)t * 3 + i;
            out[(orow * BATCH + b) * 3 + 0] = Dx;
            out[(orow * BATCH + b) * 3 + 1] = Dy;
            out[(orow * BATCH + b) * 3 + 2] = Dz;
            Ax = Bx; Ay = By; Az = Bz;
            Bx = Cx; By = Cy; Bz = Cz;
            Cx = Dx; Cy = Dy; Cz = Dz;
        }
    }
}

// =====================================================================
extern "C" void kernel_launch(void* const* d_in, const int* in_sizes, int n_in,
                              void* d_out, int out_size, void* d_ws, size_t ws_size,
                              hipStream_t stream)
{
    const float* x       = (const float*)d_in[0];
    const float* w_ih_l0 = (const float*)d_in[1];
    const float* w_hh_l0 = (const float*)d_in[2];
    const float* b_l0    = (const float*)d_in[3];
    const float* w_ih_l1 = (const float*)d_in[4];
    const float* w_hh_l1 = (const float*)d_in[5];
    const float* b_l1    = (const float*)d_in[6];
    const float* w_lin   = (const float*)d_in[7];
    const float* b_lin   = (const float*)d_in[8];
    const float* alphabet= (const float*)d_in[9];
    (void)in_sizes; (void)n_in; (void)out_size; (void)ws_size;

    char* ws = (char*)d_ws;
    unsigned int*   flags   = (unsigned int*)(ws + OFF_CNT);   // [2 launches][2 dirs][256]
    unsigned short* whhHi   = (unsigned short*)(ws + OFF_WHH_HI);
    unsigned short* whhLo   = (unsigned short*)(ws + OFF_WHH_LO);
    unsigned short* wih1Hi  = (unsigned short*)(ws + OFF_WIH1_HI);
    unsigned short* wih1Lo  = (unsigned short*)(ws + OFF_WIH1_LO);
    float*          pre     = (float*)(ws + OFF_PRE);       // pre0 then pre1 (aliased)
    unsigned short* hFHi    = (unsigned short*)(ws + OFF_H + 0 * SZ_HBUF);
    unsigned short* hFLo    = (unsigned short*)(ws + OFF_H + 1 * SZ_HBUF);
    unsigned short* hBHi    = (unsigned short*)(ws + OFF_H + 2 * SZ_HBUF);
    unsigned short* hBLo    = (unsigned short*)(ws + OFF_H + 3 * SZ_HBUF);
    unsigned short* h2FHi   = (unsigned short*)(ws + OFF_H + 4 * SZ_HBUF);
    unsigned short* h2FLo   = (unsigned short*)(ws + OFF_H + 5 * SZ_HBUF);
    unsigned short* h2BHi   = (unsigned short*)(ws + OFF_H + 6 * SZ_HBUF);
    unsigned short* h2BLo   = (unsigned short*)(ws + OFF_H + 7 * SZ_HBUF);
    float*          angbuf  = (float*)(ws + OFF_ANG);

    // zero flag arrays + boundary h slots (slot 0 for F bufs, slot 256 for B bufs)
    hipMemsetAsync(ws + OFF_CNT, 0, 4096, stream);
    const size_t slotB = (size_t)HSLOT * 2;
    hipMemsetAsync((char*)hFHi, 0, slotB, stream);
    hipMemsetAsync((char*)hFLo, 0, slotB, stream);
    hipMemsetAsync((char*)hBHi + 256 * slotB, 0, slotB, stream);
    hipMemsetAsync((char*)hBLo + 256 * slotB, 0, slotB, stream);
    hipMemsetAsync((char*)h2FHi, 0, slotB, stream);
    hipMemsetAsync((char*)h2FLo, 0, slotB, stream);
    hipMemsetAsync((char*)h2BHi + 256 * slotB, 0, slotB, stream);
    hipMemsetAsync((char*)h2BLo + 256 * slotB, 0, slotB, stream);

    pack_whh_kernel<<<5000, 256, 0, stream>>>(w_hh_l0, w_hh_l1, whhHi, whhLo);
    conv_wih1_kernel<<<5000, 256, 0, stream>>>(w_ih_l1, wih1Hi, wih1Lo);
    pre0_kernel<<<1600, 256, 0, stream>>>(x, w_ih_l0, b_l0, pre);

    // layer 0 bidirectional scan (flags[0..511])
    scan_kernel<<<NBLK_SCAN, 256, 0, stream>>>(whhHi, whhLo, pre,
                                               hFHi, hFLo, hBHi, hBLo, flags);
    // layer 1 input projection (overwrites pre in place: pre0 dead, pre1 live)
    gemm_pre1_kernel<<<6400, 256, 0, stream>>>(hFHi, hFLo, hBHi, hBLo,
                                               wih1Hi, wih1Lo, b_l1, pre);
    // layer 1 bidirectional scan (layer-1 weights; fresh flag region flags[512..1023])
    constexpr size_t LOFF = SZ_WHH_L / 2;  // ushort elements per layer
    scan_kernel<<<NBLK_SCAN, 256, 0, stream>>>(whhHi + LOFF, whhLo + LOFF, pre,
                                               h2FHi, h2FLo, h2BHi, h2BLo, flags + 512);

    head_kernel<<<L_SEQ, 256, 0, stream>>>(h2FHi, h2FLo, h2BHi, h2BLo,
                                           w_lin, b_lin, alphabet, angbuf);
    coords_kernel<<<1, 64, 0, stream>>>(angbuf, (float*)d_out);
}

// Round 4
// 6765.681 us; speedup vs baseline: 3.1897x; 1.9012x over previous
//
#include <hip/hip_runtime.h>
#include <stdint.h>

typedef __attribute__((ext_vector_type(8))) short short8;
typedef __attribute__((ext_vector_type(4))) float floatx4;

#define DEVINL __device__ __forceinline__

DEVINL unsigned short f2bf(float f) {
    unsigned int u = __float_as_uint(f);
    u += 0x7FFFu + ((u >> 16) & 1u);
    return (unsigned short)(u >> 16);
}
DEVINL float bf2f(unsigned short h) {
    return __uint_as_float(((unsigned int)h) << 16);
}
DEVINL float sigf(float x)     { return 1.0f / (1.0f + __expf(-x)); }
DEVINL float tanhfast(float x) { return 2.0f / (1.0f + __expf(-2.0f * x)) - 1.0f; }

// ---------------- problem constants ----------------
constexpr int L_SEQ = 256, BATCH = 16, HID = 800, NGATE = 3200, DIN = 42, NALPHA = 20;
constexpr int HSLOT = BATCH * HID;          // 12800 elements per time slot
constexpr int NBLK_SCAN = 200;              // 2 dirs x 100 j-chunks (8 hidden units each)

// ---------------- workspace layout (bytes) ----------------
// hi/lo split-bf16 weights; h archives packed (hi|lo<<16) u32; fp32 pre.
constexpr size_t OFF_CNT     = 0;                                   // 4 KB flag arrays
constexpr size_t SZ_WHH_L    = 10240000;                            // per layer: 2*3200*800*2B
constexpr size_t OFF_WHH_HI  = 4096;                                // 2 layers
constexpr size_t OFF_WHH_LO  = OFF_WHH_HI + 2 * SZ_WHH_L;
constexpr size_t SZ_WIH1     = 20480000;                            // 2*3200*1600*2B
constexpr size_t OFF_WIH1_HI = OFF_WHH_LO + 2 * SZ_WHH_L;
constexpr size_t OFF_WIH1_LO = OFF_WIH1_HI + SZ_WIH1;
constexpr size_t OFF_PRE     = OFF_WIH1_LO + SZ_WIH1;               // fp32, shared pre0/pre1
constexpr size_t SZ_PRE      = (size_t)2 * L_SEQ * BATCH * NGATE * 4;  // 104,857,600
constexpr size_t SZ_HP       = (size_t)257 * HSLOT * 4;             // 13,158,400 per packed buf
constexpr size_t OFF_H       = OFF_PRE + SZ_PRE;                    // 4 bufs: F, B, 2F, 2B
constexpr size_t OFF_ANG     = OFF_H + 4 * SZ_HP;                   // 256*16*3 fp32
// total ~228.4 MiB

// Unpack 8 consecutive packed h elements via device-scope (sc1) 64-bit loads.
DEVINL void load_unpack8_agent(const uint32_t* p, short8& ah, short8& al) {
    #pragma unroll
    for (int j = 0; j < 4; ++j) {
        unsigned long long u = __hip_atomic_load(
            (const unsigned long long*)(p + 2 * j),
            __ATOMIC_RELAXED, __HIP_MEMORY_SCOPE_AGENT);
        ah[2 * j]     = (short)(u & 0xffffull);
        al[2 * j]     = (short)((u >> 16) & 0xffffull);
        ah[2 * j + 1] = (short)((u >> 32) & 0xffffull);
        al[2 * j + 1] = (short)(u >> 48);
    }
}

// =====================================================================
// Pack W_hh (fp32 [2][3200][800]) into hi/lo MFMA B-fragment streams.
// =====================================================================
__global__ __launch_bounds__(256) void pack_whh_kernel(
    const float* __restrict__ w0, const float* __restrict__ w1,
    unsigned short* __restrict__ hi, unsigned short* __restrict__ lo)
{
    size_t g = (size_t)blockIdx.x * 256 + threadIdx.x;   // 1,280,000 total
    if (g >= 1280000) return;
    int l = (int)(g & 63);
    size_t gg = g >> 6;                                   // 20000 fragment ids
    int kk = (int)(gg % 25); gg /= 25;
    int nt = (int)(gg % 2);  gg /= 2;
    int jc = (int)(gg % 100); gg /= 100;
    int d  = (int)(gg % 2);
    int layer = (int)(gg / 2);
    const float* W = layer ? w1 : w0;
    int lr = nt * 16 + (l & 15);
    int gate = lr >> 3, jj = lr & 7;
    int r  = gate * 800 + jc * 8 + jj;
    int k0 = kk * 32 + (l >> 4) * 8;
    const float* s = W + ((size_t)d * NGATE + r) * HID + k0;
    short8 vh, vl;
    #pragma unroll
    for (int j = 0; j < 8; ++j) {
        float w = s[j];
        unsigned short h = f2bf(w);
        vh[j] = (short)h;
        vl[j] = (short)f2bf(w - bf2f(h));
    }
    size_t idx = (size_t)layer * 640000 + ((size_t)d * 100 + jc) * 3200
               + (size_t)(nt * 25 + kk) * 64 + l;
    ((short8*)hi)[idx] = vh;
    ((short8*)lo)[idx] = vl;
}

// =====================================================================
// fp32 -> hi/lo bf16 conversion of w_ih_l1 (flat [2][3200][1600]).
// =====================================================================
__global__ __launch_bounds__(256) void conv_wih1_kernel(
    const float* __restrict__ w, unsigned short* __restrict__ hi,
    unsigned short* __restrict__ lo)
{
    size_t g = (size_t)blockIdx.x * 256 + threadIdx.x;   // 1,280,000 groups of 8
    if (g >= 1280000) return;
    const float* s = w + g * 8;
    short8 vh, vl;
    #pragma unroll
    for (int j = 0; j < 8; ++j) {
        float x = s[j];
        unsigned short h = f2bf(x);
        vh[j] = (short)h;
        vl[j] = (short)f2bf(x - bf2f(h));
    }
    ((short8*)hi)[g] = vh;
    ((short8*)lo)[g] = vl;
}

// =====================================================================
// pre0[d][t][b][r] = x[t,b,:] @ w_ih_l0[d].T + b_l0[d]   (fp32 out)
// =====================================================================
__global__ __launch_bounds__(256) void pre0_kernel(
    const float* __restrict__ x, const float* __restrict__ wih0,
    const float* __restrict__ b0, float* __restrict__ pre0)
{
    int bid = blockIdx.x;
    int d = bid / 800; int rem = bid % 800;
    int rc = rem / 8, tc = rem % 8;
    int rbase = rc * 32, tbase = tc * 32;
    __shared__ float Wc[32][DIN];
    __shared__ float bias[32];
    __shared__ float xb[BATCH][DIN];
    int tid = threadIdx.x;
    for (int idx = tid; idx < 32 * DIN; idx += 256) {
        int rl = idx / DIN, k = idx % DIN;
        Wc[rl][k] = wih0[((size_t)d * NGATE + rbase + rl) * DIN + k];
    }
    if (tid < 32) bias[tid] = b0[d * NGATE + rbase + tid];
    __syncthreads();
    for (int tt = 0; tt < 32; ++tt) {
        int t = tbase + tt;
        for (int idx = tid; idx < BATCH * DIN; idx += 256) {
            int bb = idx / DIN, k = idx % DIN;
            xb[bb][k] = x[((size_t)bb * L_SEQ + t) * DIN + k];
        }
        __syncthreads();
        for (int o = tid; o < 512; o += 256) {
            int bb = o >> 5, rl = o & 31;
            float s = bias[rl];
            #pragma unroll 6
            for (int k = 0; k < DIN; ++k) s += xb[bb][k] * Wc[rl][k];
            pre0[((size_t)(d * L_SEQ + t) * BATCH + bb) * NGATE + rbase + rl] = s;
        }
        __syncthreads();
    }
}

// =====================================================================
// Persistent bidirectional LSTM scan (split-precision bf16 hi/lo).
// h handoff is fully device-scope (sc1 atomics, packed hi|lo u32):
// NO __threadfence (no buffer_wbl2/buffer_inv per step). Producer h
// stores drain at the pre-barrier vmcnt(0); flag store is relaxed-agent;
// consumers read h with sc1 loads that bypass stale L1/L2.
// =====================================================================
__global__ __launch_bounds__(256, 1) void scan_kernel(
    const unsigned short* __restrict__ wpackH,
    const unsigned short* __restrict__ wpackL,
    const float* __restrict__ pre,              // [d][t][b][3200] fp32
    uint32_t* hFP, uint32_t* hBP,               // packed h archives [257][16][800]
    unsigned int* flags)                        // [2][256] uints, per-dir
{
    __shared__ __align__(16) unsigned short wldsH[25600];   // 51.2 KB
    __shared__ __align__(16) unsigned short wldsL[25600];   // 51.2 KB
    __shared__ __align__(16) float exch[2][2][64][4];       // [nt][kh][lane][reg]
    __shared__ float cbuf[128];
    int tid = threadIdx.x;
    int bid = blockIdx.x;
    int d = bid / 100, jc = bid % 100;
    unsigned int* dirFlags = flags + (size_t)d * 256;

    {   // load weight fragments once (plain loads; fresh L2 at dispatch)
        const short8* sh = (const short8*)wpackH + ((size_t)d * 100 + jc) * 3200;
        const short8* sl = (const short8*)wpackL + ((size_t)d * 100 + jc) * 3200;
        short8* dh = (short8*)wldsH;
        short8* dl = (short8*)wldsL;
        for (int i = tid; i < 3200; i += 256) { dh[i] = sh[i]; dl[i] = sl[i]; }
    }
    if (tid < 128) cbuf[tid] = 0.0f;
    __syncthreads();

    int lane = tid & 63, w = tid >> 6;
    int nt = w & 1, kh = w >> 1;
    int kkS = kh ? 13 : 0, kkE = kh ? 25 : 13;
    int bA = lane & 15, q = lane >> 4;

    uint32_t* hOutP = d ? hBP : hFP;
    const uint32_t* hInP = d ? hBP : hFP;

    for (int s = 0; s < L_SEQ; ++s) {
        int t = d ? (L_SEQ - 1 - s) : s;
        const uint32_t* hin = hInP + (size_t)(d ? (t + 1) : t) * HSLOT;

        floatx4 acc = {0.f, 0.f, 0.f, 0.f};
        for (int kk = kkS; kk < kkE; ++kk) {
            int k0 = kk * 32 + q * 8;
            short8 ah, al;
            load_unpack8_agent(hin + bA * HID + k0, ah, al);
            short8 bh = ((const short8*)wldsH)[(nt * 25 + kk) * 64 + lane];
            short8 bl = ((const short8*)wldsL)[(nt * 25 + kk) * 64 + lane];
            acc = __builtin_amdgcn_mfma_f32_16x16x32_bf16(ah, bh, acc, 0, 0, 0);
            acc = __builtin_amdgcn_mfma_f32_16x16x32_bf16(ah, bl, acc, 0, 0, 0);
            acc = __builtin_amdgcn_mfma_f32_16x16x32_bf16(al, bh, acc, 0, 0, 0);
        }
        *(floatx4*)&exch[nt][kh][lane][0] = acc;
        __syncthreads();

        if (tid < 128) {
            int bb = tid >> 3, jl = tid & 7;
            float G[4];
            #pragma unroll
            for (int gate = 0; gate < 4; ++gate) {
                int lr = gate * 8 + jl;
                int nt2 = lr >> 4, n = lr & 15;
                int ln = ((bb >> 2) << 4) | n;
                int rg = bb & 3;
                float pv = pre[((size_t)(d * L_SEQ + t) * BATCH + bb) * NGATE
                               + gate * 800 + jc * 8 + jl];
                G[gate] = exch[nt2][0][ln][rg] + exch[nt2][1][ln][rg] + pv;
            }
            float i_ = sigf(G[0]), f_ = sigf(G[1]);
            float g_ = tanhfast(G[2]), o_ = sigf(G[3]);
            float c = f_ * cbuf[tid] + i_ * g_;
            cbuf[tid] = c;
            float h = o_ * tanhfast(c);
            size_t oslot = (size_t)(d ? t : (t + 1)) * HSLOT;
            size_t oidx = oslot + bb * HID + jc * 8 + jl;
            unsigned short hh = f2bf(h);
            unsigned int pk = (unsigned int)hh
                            | ((unsigned int)f2bf(h - bf2f(hh)) << 16);
            // device-scope write-through store: visible at coherence point,
            // no L2 flush required
            __hip_atomic_store(&hOutP[oidx], pk, __ATOMIC_RELAXED,
                               __HIP_MEMORY_SCOPE_AGENT);
        }
        __syncthreads();   // compiler emits s_waitcnt vmcnt(0) first: sc1 stores drained

        unsigned int tgt = (unsigned int)(s + 1);
        if (tid == 0) {
            __hip_atomic_store(&dirFlags[jc], tgt, __ATOMIC_RELAXED,
                               __HIP_MEMORY_SCOPE_AGENT);
        }
        if (tid < 64) {        // wave 0 polls all 100 flags in parallel
            bool ok;
            do {
                bool a = (tid < 100)
                    ? (__hip_atomic_load(&dirFlags[tid], __ATOMIC_RELAXED,
                                         __HIP_MEMORY_SCOPE_AGENT) >= tgt) : true;
                bool b = (tid + 64 < 100)
                    ? (__hip_atomic_load(&dirFlags[tid + 64], __ATOMIC_RELAXED,
                                         __HIP_MEMORY_SCOPE_AGENT) >= tgt) : true;
                ok = __all(a && b);
            } while (!ok);
        }
        __syncthreads();       // full compiler + HW barrier; h reads below are sc1
    }
}

// =====================================================================
// pre1[d][t][b][r] = concat(h1f[t], h1b[t]) @ w_ih_l1[d].T + b_l1[d]  (fp32)
// split-precision 64x64-tile MFMA GEMM: M=4096 (t,b), N=3200, K=1600.
// A read from packed h archives (plain loads; kernel boundary = acquire).
// =====================================================================
__global__ __launch_bounds__(256, 1) void gemm_pre1_kernel(
    const uint32_t* __restrict__ hFP, const uint32_t* __restrict__ hBP,
    const unsigned short* __restrict__ wih1H, const unsigned short* __restrict__ wih1L,
    const float* __restrict__ b1, float* __restrict__ pre1)
{
    int bid = blockIdx.x;
    int d = bid / 3200; int rst = bid % 3200;
    int mblk = rst / 50, nblk = rst % 50;
    __shared__ __align__(16) unsigned short AslH[64][40];
    __shared__ __align__(16) unsigned short AslL[64][40];
    __shared__ __align__(16) unsigned short BslH[64][40];
    __shared__ __align__(16) unsigned short BslL[64][40];
    int tid = threadIdx.x, lane = tid & 63, w = tid >> 6;
    int wm = w >> 1, wn = w & 1;
    floatx4 acc[2][2] = {};
    int row = tid >> 2, ch = tid & 3;
    int m_row = mblk * 64 + row;
    int t = m_row >> 4, bb = m_row & 15;
    int la = lane & 15, q8 = (lane >> 4) * 8;

    for (int kk = 0; kk < 50; ++kk) {
        int k0 = kk * 32 + ch * 8;
        size_t aoff = (kk < 25)
            ? ((size_t)(t + 1) * HSLOT + bb * HID + k0)
            : ((size_t)t * HSLOT + bb * HID + (k0 - 800));
        const uint32_t* ap = ((kk < 25) ? hFP : hBP) + aoff;
        uint4 p0 = *(const uint4*)ap;
        uint4 p1 = *(const uint4*)(ap + 4);
        short8 ah, al;
        ah[0]=(short)(p0.x&0xffffu); al[0]=(short)(p0.x>>16);
        ah[1]=(short)(p0.y&0xffffu); al[1]=(short)(p0.y>>16);
        ah[2]=(short)(p0.z&0xffffu); al[2]=(short)(p0.z>>16);
        ah[3]=(short)(p0.w&0xffffu); al[3]=(short)(p0.w>>16);
        ah[4]=(short)(p1.x&0xffffu); al[4]=(short)(p1.x>>16);
        ah[5]=(short)(p1.y&0xffffu); al[5]=(short)(p1.y>>16);
        ah[6]=(short)(p1.z&0xffffu); al[6]=(short)(p1.z>>16);
        ah[7]=(short)(p1.w&0xffffu); al[7]=(short)(p1.w>>16);
        *(short8*)&AslH[row][ch * 8] = ah;
        *(short8*)&AslL[row][ch * 8] = al;
        size_t boff = ((size_t)d * NGATE + nblk * 64 + row) * 1600 + kk * 32 + ch * 8;
        *(short8*)&BslH[row][ch * 8] = *(const short8*)(wih1H + boff);
        *(short8*)&BslL[row][ch * 8] = *(const short8*)(wih1L + boff);
        __syncthreads();
        #pragma unroll
        for (int ms = 0; ms < 2; ++ms) {
            short8 fah = *(const short8*)&AslH[wm * 32 + ms * 16 + la][q8];
            short8 fal = *(const short8*)&AslL[wm * 32 + ms * 16 + la][q8];
            #pragma unroll
            for (int ns = 0; ns < 2; ++ns) {
                short8 fbh = *(const short8*)&BslH[wn * 32 + ns * 16 + la][q8];
                short8 fbl = *(const short8*)&BslL[wn * 32 + ns * 16 + la][q8];
                acc[ms][ns] = __builtin_amdgcn_mfma_f32_16x16x32_bf16(fah, fbh, acc[ms][ns], 0, 0, 0);
                acc[ms][ns] = __builtin_amdgcn_mfma_f32_16x16x32_bf16(fah, fbl, acc[ms][ns], 0, 0, 0);
                acc[ms][ns] = __builtin_amdgcn_mfma_f32_16x16x32_bf16(fal, fbh, acc[ms][ns], 0, 0, 0);
            }
        }
        __syncthreads();
    }
    #pragma unroll
    for (int ms = 0; ms < 2; ++ms)
        #pragma unroll
        for (int ns = 0; ns < 2; ++ns)
            #pragma unroll
            for (int rg = 0; rg < 4; ++rg) {
                int m = mblk * 64 + wm * 32 + ms * 16 + (lane >> 4) * 4 + rg;
                int t2 = m >> 4, b2 = m & 15;
                int r = nblk * 64 + wn * 32 + ns * 16 + (lane & 15);
                float val = acc[ms][ns][rg] + b1[d * NGATE + r];
                pre1[((size_t)(d * L_SEQ + t2) * BATCH + b2) * NGATE + r] = val;
            }
}

// =====================================================================
// Head: logits -> softmax -> torsion angles.  One block per t.
// =====================================================================
__global__ __launch_bounds__(256) void head_kernel(
    const uint32_t* __restrict__ h2FP, const uint32_t* __restrict__ h2BP,
    const float* __restrict__ wlin, const float* __restrict__ blin,
    const float* __restrict__ alphabet, float* __restrict__ ang)
{
    int t = blockIdx.x, tid = threadIdx.x;
    __shared__ float lg[BATCH * NALPHA];
    __shared__ float probs[BATCH * NALPHA];
    for (int i = tid; i < BATCH * NALPHA; i += 256) {
        int a = i % NALPHA, b = i / NALPHA;
        size_t fo = (size_t)(t + 1) * HSLOT + b * HID;
        size_t bo = (size_t)t * HSLOT + b * HID;
        const float* wa = wlin + (size_t)a * 1600;
        float s = blin[a];
        #pragma unroll 4
        for (int k = 0; k < HID; ++k) {
            uint32_t uf = h2FP[fo + k], ub = h2BP[bo + k];
            float hf = bf2f((unsigned short)uf) + bf2f((unsigned short)(uf >> 16));
            float hb = bf2f((unsigned short)ub) + bf2f((unsigned short)(ub >> 16));
            s += hf * wa[k] + hb * wa[800 + k];
        }
        lg[b * NALPHA + a] = s;
    }
    __syncthreads();
    if (tid < BATCH) {
        int b = tid;
        float mx = -1e30f;
        for (int a = 0; a < NALPHA; ++a) mx = fmaxf(mx, lg[b * NALPHA + a]);
        float sum = 0.f;
        for (int a = 0; a < NALPHA; ++a) {
            float e = __expf(lg[b * NALPHA + a] - mx);
            probs[b * NALPHA + a] = e; sum += e;
        }
        float inv = 1.0f / sum;
        for (int a = 0; a < NALPHA; ++a) probs[b * NALPHA + a] *= inv;
    }
    __syncthreads();
    if (tid < BATCH * 3) {
        int b = tid / 3, i = tid % 3;
        float ss = 0.f, cc = 0.f;
        for (int a = 0; a < NALPHA; ++a) {
            float al = alphabet[a * 3 + i], p = probs[b * NALPHA + a];
            ss += p * sinf(al); cc += p * cosf(al);
        }
        ang[((size_t)t * BATCH + b) * 3 + i] = atan2f(ss, cc);
    }
}

// =====================================================================
// Sequential NeRF coordinate chain. One block; lane b handles batch b.
// =====================================================================
__global__ __launch_bounds__(64) void coords_kernel(
    const float* __restrict__ ang, float* __restrict__ out)
{
    int b = threadIdx.x;
    if (b >= BATCH) return;
    const float LENS[3] = {145.801f, 152.326f, 132.868f};
    const float ANGS[3] = {2.124f, 1.941f, 2.028f};
    float Ax = 0.f, Ay = 0.f, Az = 1.f;
    float Bx = 0.f, By = 1.f, Bz = 0.f;
    float Cx = 1.f, Cy = 0.f, Cz = 0.f;
    out[((size_t)0 * BATCH + b) * 3 + 0] = 0.f; out[((size_t)0 * BATCH + b) * 3 + 1] = 0.f; out[((size_t)0 * BATCH + b) * 3 + 2] = 1.f;
    out[((size_t)1 * BATCH + b) * 3 + 0] = 0.f; out[((size_t)1 * BATCH + b) * 3 + 1] = 1.f; out[((size_t)1 * BATCH + b) * 3 + 2] = 0.f;
    out[((size_t)2 * BATCH + b) * 3 + 0] = 1.f; out[((size_t)2 * BATCH + b) * 3 + 1] = 0.f; out[((size_t)2 * BATCH + b) * 3 + 2] = 0.f;
    for (int t = 0; t < L_SEQ; ++t) {
        #pragma unroll
        for (int i = 0; i < 3; ++i) {
            float P = ang[((size_t)t * BATCH + b) * 3 + i];
            float R = LENS[i], T = ANGS[i];
            float sT = sinf(T);
            float D2x = -R * cosf(T);
            float D2y = R * cosf(P) * sT;
            float D2z = R * sinf(P) * sT;
            float bx = Cx - Bx, by = Cy - By, bz = Cz - Bz;
            float binv = 1.0f / sqrtf(bx * bx + by * by + bz * bz);
            bx *= binv; by *= binv; bz *= binv;
            float ux = Bx - Ax, uy = By - Ay, uz = Bz - Az;
            float nx = uy * bz - uz * by;
            float ny = uz * bx - ux * bz;
            float nz = ux * by - uy * bx;
            float ninv = 1.0f / sqrtf(nx * nx + ny * ny + nz * nz);
            nx *= ninv; ny *= ninv; nz *= ninv;
            float cxx = ny * bz - nz * by;
            float cxy = nz * bx - nx * bz;
            float cxz = nx * by - ny * bx;
            float Dx = bx * D2x + cxx * D2y + nx * D2z + Cx;
            float Dy = by * D2x + cxy * D2y + ny * D2z + Cy;
            float Dz = bz * D2x + cxz * D2y + nz * D2z + Cz;
            size_t orow = 3 + (size_t)t * 3 + i;
            out[(orow * BATCH + b) * 3 + 0] = Dx;
            out[(orow * BATCH + b) * 3 + 1] = Dy;
            out[(orow * BATCH + b) * 3 + 2] = Dz;
            Ax = Bx; Ay = By; Az = Bz;
            Bx = Cx; By = Cy; Bz = Cz;
            Cx = Dx; Cy = Dy; Cz = Dz;
        }
    }
}

// =====================================================================
extern "C" void kernel_launch(void* const* d_in, const int* in_sizes, int n_in,
                              void* d_out, int out_size, void* d_ws, size_t ws_size,
                              hipStream_t stream)
{
    const float* x       = (const float*)d_in[0];
    const float* w_ih_l0 = (const float*)d_in[1];
    const float* w_hh_l0 = (const float*)d_in[2];
    const float* b_l0    = (const float*)d_in[3];
    const float* w_ih_l1 = (const float*)d_in[4];
    const float* w_hh_l1 = (const float*)d_in[5];
    const float* b_l1    = (const float*)d_in[6];
    const float* w_lin   = (const float*)d_in[7];
    const float* b_lin   = (const float*)d_in[8];
    const float* alphabet= (const float*)d_in[9];
    (void)in_sizes; (void)n_in; (void)out_size; (void)ws_size;

    char* ws = (char*)d_ws;
    unsigned int*   flags   = (unsigned int*)(ws + OFF_CNT);   // [2 launches][2 dirs][256]
    unsigned short* whhHi   = (unsigned short*)(ws + OFF_WHH_HI);
    unsigned short* whhLo   = (unsigned short*)(ws + OFF_WHH_LO);
    unsigned short* wih1Hi  = (unsigned short*)(ws + OFF_WIH1_HI);
    unsigned short* wih1Lo  = (unsigned short*)(ws + OFF_WIH1_LO);
    float*          pre     = (float*)(ws + OFF_PRE);       // pre0 then pre1 (aliased)
    uint32_t*       hFP     = (uint32_t*)(ws + OFF_H + 0 * SZ_HP);
    uint32_t*       hBP     = (uint32_t*)(ws + OFF_H + 1 * SZ_HP);
    uint32_t*       h2FP    = (uint32_t*)(ws + OFF_H + 2 * SZ_HP);
    uint32_t*       h2BP    = (uint32_t*)(ws + OFF_H + 3 * SZ_HP);
    float*          angbuf  = (float*)(ws + OFF_ANG);

    // zero flag arrays + boundary h slots (slot 0 for F bufs, slot 256 for B bufs)
    hipMemsetAsync(ws + OFF_CNT, 0, 4096, stream);
    const size_t slotB = (size_t)HSLOT * 4;
    hipMemsetAsync((char*)hFP, 0, slotB, stream);
    hipMemsetAsync((char*)hBP + 256 * slotB, 0, slotB, stream);
    hipMemsetAsync((char*)h2FP, 0, slotB, stream);
    hipMemsetAsync((char*)h2BP + 256 * slotB, 0, slotB, stream);

    pack_whh_kernel<<<5000, 256, 0, stream>>>(w_hh_l0, w_hh_l1, whhHi, whhLo);
    conv_wih1_kernel<<<5000, 256, 0, stream>>>(w_ih_l1, wih1Hi, wih1Lo);
    pre0_kernel<<<1600, 256, 0, stream>>>(x, w_ih_l0, b_l0, pre);

    // layer 0 bidirectional scan (flags[0..511])
    scan_kernel<<<NBLK_SCAN, 256, 0, stream>>>(whhHi, whhLo, pre, hFP, hBP, flags);
    // layer 1 input projection (overwrites pre in place: pre0 dead, pre1 live)
    gemm_pre1_kernel<<<6400, 256, 0, stream>>>(hFP, hBP, wih1Hi, wih1Lo, b_l1, pre);
    // layer 1 bidirectional scan (layer-1 weights; fresh flag region flags[512..1023])
    constexpr size_t LOFF = SZ_WHH_L / 2;  // ushort elements per layer
    scan_kernel<<<NBLK_SCAN, 256, 0, stream>>>(whhHi + LOFF, whhLo + LOFF, pre,
                                               h2FP, h2BP, flags + 512);

    head_kernel<<<L_SEQ, 256, 0, stream>>>(h2FP, h2BP, w_lin, b_lin, alphabet, angbuf);
    coords_kernel<<<1, 64, 0, stream>>>(angbuf, (float*)d_out);
}